// Round 1
// baseline (2144.491 us; speedup 1.0000x reference)
//
#include <hip/hip_runtime.h>
#include <hip/hip_bf16.h>

#define Bb 16
#define Tt 512
#define Hh 1024
#define NHd 16
#define HD 64
#define BT (Bb*Tt)
#define NSK 50
#define NIT 1000

// ---------------- skill masks: item -> bitmask of skills ----------------
__global__ void k_skill_mask(const float* __restrict__ qm, unsigned long long* __restrict__ smask){
  int p = blockIdx.x*blockDim.x + threadIdx.x;
  if (p >= NIT) return;
  unsigned long long m = 0ull;
  #pragma unroll
  for (int s = 0; s < NSK; s++)
    if (qm[s*NIT + p] != 0.f) m |= (1ull << s);
  smask[p] = m;
}

__global__ void k_pid_mask(const int* __restrict__ prob_x,
                           const unsigned long long* __restrict__ smask,
                           unsigned long long* __restrict__ pmask){
  int i = blockIdx.x*blockDim.x + threadIdx.x;
  if (i >= BT) return;
  int pid = (prob_x[i] - 4) >> 1;
  pmask[i] = smask[pid];
}

// ---------------- x = emb[prob_x] + position encoding ----------------
__global__ void k_build_x(const int* __restrict__ prob_x, const float* __restrict__ emb,
                          float* __restrict__ x){
  int bt = blockIdx.x;
  int tid = threadIdx.x;
  int t = bt & (Tt - 1);
  int ix = prob_x[bt];
  const float LOG_INC = 0.0180241495f;   // ln(10000)/511
  for (int h = tid; h < Hh; h += 256){
    int j = h >> 1;
    float ang = (float)t * expf(-(float)j * LOG_INC);
    float pe = (h & 1) ? cosf(ang) : sinf(ang);
    x[(size_t)bt*Hh + h] = emb[(size_t)ix*Hh + h] + pe;
  }
}

// ---------------- fp32 GEMM, 128x128 tile, 8x8 per thread ----------------
// A: MxK row-major (M=8192, K=1024), Bw: KxN row-major (N=1024).
// scatter=1: write C as (b, n, t, d) with scale (for q/k/v).
// scatter=0: C[m*N+c] = acc + res[m*N+c]  (WO projection + residual).
__global__ __launch_bounds__(256) void k_gemm128(
    const float* __restrict__ A, const float* __restrict__ Bw,
    float* __restrict__ C, const float* __restrict__ res,
    float scale, int scatter)
{
  const int K = 1024, N = 1024;
  __shared__ float As[16][132];
  __shared__ float Bs[16][132];
  int tid = threadIdx.x;
  int tx = tid & 15, ty = tid >> 4;
  int row0 = blockIdx.y * 128, col0 = blockIdx.x * 128;
  float acc[8][8];
  #pragma unroll
  for (int i = 0; i < 8; i++)
    #pragma unroll
    for (int j = 0; j < 8; j++) acc[i][j] = 0.f;

  int ar = tid >> 2, ac = (tid & 3) * 4;   // A tile: rows ar, ar+64; k-cols ac..ac+3
  int br = tid >> 5, bc = (tid & 31) * 4;  // B tile: k-rows br, br+8; cols bc..bc+3
  const float* Ap0 = A + (size_t)(row0 + ar) * K + ac;
  const float* Ap1 = A + (size_t)(row0 + ar + 64) * K + ac;
  const float* Bp0 = Bw + (size_t)br * N + col0 + bc;
  const float* Bp1 = Bw + (size_t)(br + 8) * N + col0 + bc;

  for (int k0 = 0; k0 < K; k0 += 16){
    float4 a0 = *(const float4*)(Ap0 + k0);
    float4 a1 = *(const float4*)(Ap1 + k0);
    float4 b0 = *(const float4*)(Bp0 + (size_t)k0 * N);
    float4 b1 = *(const float4*)(Bp1 + (size_t)k0 * N);
    __syncthreads();
    As[ac+0][ar] = a0.x; As[ac+1][ar] = a0.y; As[ac+2][ar] = a0.z; As[ac+3][ar] = a0.w;
    As[ac+0][ar+64] = a1.x; As[ac+1][ar+64] = a1.y; As[ac+2][ar+64] = a1.z; As[ac+3][ar+64] = a1.w;
    *(float4*)&Bs[br][bc]   = b0;
    *(float4*)&Bs[br+8][bc] = b1;
    __syncthreads();
    #pragma unroll
    for (int kk = 0; kk < 16; kk++){
      float a[8], b[8];
      *(float4*)(a)   = *(const float4*)&As[kk][ty*8];
      *(float4*)(a+4) = *(const float4*)&As[kk][ty*8+4];
      *(float4*)(b)   = *(const float4*)&Bs[kk][tx*8];
      *(float4*)(b+4) = *(const float4*)&Bs[kk][tx*8+4];
      #pragma unroll
      for (int i = 0; i < 8; i++)
        #pragma unroll
        for (int j = 0; j < 8; j++)
          acc[i][j] = fmaf(a[i], b[j], acc[i][j]);
    }
  }

  if (scatter){
    #pragma unroll
    for (int i = 0; i < 8; i++){
      int m = row0 + ty*8 + i;
      int b_ = m >> 9, t_ = m & (Tt - 1);
      #pragma unroll
      for (int j = 0; j < 8; j++){
        int c = col0 + tx*8 + j;
        int n_ = c >> 6, d_ = c & 63;
        C[(((size_t)b_*NHd + n_)*Tt + t_)*HD + d_] = acc[i][j] * scale;
      }
    }
  } else {
    #pragma unroll
    for (int i = 0; i < 8; i++){
      int m = row0 + ty*8 + i;
      #pragma unroll
      for (int j = 0; j < 8; j++){
        int c = col0 + tx*8 + j;
        size_t idx = (size_t)m*N + c;
        C[idx] = acc[i][j] + res[idx];
      }
    }
  }
}

// ---------------- attention: one wave per (b, n, f) query row ----------------
// q,k,v layout (b, n, t, d); output (b, t, n, d).
__global__ __launch_bounds__(256) void k_attn(
    const float* __restrict__ q, const float* __restrict__ k,
    const float* __restrict__ v, const unsigned long long* __restrict__ pmask,
    float* __restrict__ o)
{
  __shared__ float sL[4][Tt];
  __shared__ float sQ[4][HD];
  int wave = threadIdx.x >> 6;
  int lane = threadIdx.x & 63;
  int f = blockIdx.x * 4 + wave;
  int bn = blockIdx.y;
  int b = bn >> 4, n = bn & 15;

  sQ[wave][lane] = q[((size_t)bn*Tt + f)*HD + lane];
  unsigned long long mf = pmask[b*Tt + f];
  __syncthreads();   // uniform: executed by all threads before divergence

  const float* kbase = k + (size_t)bn*Tt*HD;
  const float* vbase = v + (size_t)bn*Tt*HD;
  const unsigned long long* pm = pmask + b*Tt;

  float lmax = -INFINITY;
  for (int t = lane; t <= f; t += 64){
    bool allowed = (f == 0) ? (t == 0) : (t > 0 && (pm[t] & mf));
    if (allowed){
      const float* kr = kbase + (size_t)t*HD;
      float dot = 0.f;
      #pragma unroll
      for (int d = 0; d < HD; d += 4){
        float4 kv = *(const float4*)(kr + d);
        dot += sQ[wave][d]*kv.x + sQ[wave][d+1]*kv.y + sQ[wave][d+2]*kv.z + sQ[wave][d+3]*kv.w;
      }
      sL[wave][t] = dot;
      lmax = fmaxf(lmax, dot);
    } else {
      sL[wave][t] = -INFINITY;
    }
  }
  #pragma unroll
  for (int off = 32; off; off >>= 1) lmax = fmaxf(lmax, __shfl_xor(lmax, off));

  float lsum = 0.f;
  for (int t = lane; t <= f; t += 64){
    float e = __expf(sL[wave][t] - lmax);  // exp(-inf) = 0 for masked
    sL[wave][t] = e;
    lsum += e;
  }
  #pragma unroll
  for (int off = 32; off; off >>= 1) lsum += __shfl_xor(lsum, off);
  float inv = 1.f / lsum;

  float acc = 0.f;
  #pragma unroll 4
  for (int t = 0; t <= f; t++)
    acc += sL[wave][t] * vbase[(size_t)t*HD + lane];

  o[(((size_t)b*Tt + f)*NHd + n)*HD + lane] = acc * inv;
}

// ---------------- LN + MLP head + gather, one block per (b,t) row ----------------
__global__ __launch_bounds__(256) void k_head(
    const float* __restrict__ ypre, const int* __restrict__ prob_y2,
    const float* __restrict__ gamma, const float* __restrict__ beta,
    const float* __restrict__ w_hid, const float* __restrict__ b_hid,
    const float* __restrict__ w_skill, const float* __restrict__ b_skill,
    const float* __restrict__ w_prob, const float* __restrict__ b_prob,
    float* __restrict__ out)
{
  int bt = blockIdx.x;
  int tid = threadIdx.x;
  __shared__ float yn[Hh];
  __shared__ float red[256];
  __shared__ float hbuf[128];
  __shared__ float sk[64];
  const float* yr = ypre + (size_t)bt*Hh;

  float vals[4], s1 = 0.f, s2 = 0.f;
  #pragma unroll
  for (int i = 0; i < 4; i++){
    float vv = yr[tid + 256*i];
    vals[i] = vv; s1 += vv; s2 += vv*vv;
  }
  red[tid] = s1; __syncthreads();
  for (int s = 128; s; s >>= 1){ if (tid < s) red[tid] += red[tid+s]; __syncthreads(); }
  float mu = red[0] * (1.f/Hh); __syncthreads();
  red[tid] = s2; __syncthreads();
  for (int s = 128; s; s >>= 1){ if (tid < s) red[tid] += red[tid+s]; __syncthreads(); }
  float var = red[0] * (1.f/Hh) - mu*mu;
  float inv = rsqrtf(var + 1e-3f);
  #pragma unroll
  for (int i = 0; i < 4; i++){
    int h = tid + 256*i;
    yn[h] = (vals[i] - mu) * inv * gamma[h] + beta[h];
  }
  __syncthreads();

  // h = relu(yn @ w_hid + b_hid): 100 cols, 2-way K split
  int j = tid & 127, part = tid >> 7;
  float hs = 0.f;
  if (j < 100){
    int i0 = part * 512;
    for (int i = i0; i < i0 + 512; i++) hs += yn[i] * w_hid[i*100 + j];
  }
  red[tid] = hs; __syncthreads();
  if (tid < 128){
    float hv = red[tid] + red[tid + 128];
    if (tid < 100) hbuf[tid] = fmaxf(hv + b_hid[tid], 0.f);
  }
  __syncthreads();

  if (tid < 50){
    float s = b_skill[tid];
    for (int i = 0; i < 100; i++) s += hbuf[i] * w_skill[i*50 + tid];
    sk[tid] = s;
  }
  __syncthreads();

  if (tid == 0){
    int np = (prob_y2[bt] - 4) >> 1;
    float z = b_prob[np];
    #pragma unroll
    for (int s = 0; s < NSK; s++) z += sk[s] * w_prob[s*NIT + np];
    out[bt] = 1.f / (1.f + expf(-z));
  }
}

extern "C" void kernel_launch(void* const* d_in, const int* in_sizes, int n_in,
                              void* d_out, int out_size, void* d_ws, size_t ws_size,
                              hipStream_t stream)
{
  const int*   prob_x   = (const int*)d_in[0];
  const int*   prob_y2  = (const int*)d_in[1];
  const float* emb      = (const float*)d_in[2];
  const float* wq       = (const float*)d_in[3];
  const float* wk       = (const float*)d_in[4];
  const float* wv       = (const float*)d_in[5];
  const float* wo       = (const float*)d_in[6];
  const float* ln_g     = (const float*)d_in[7];
  const float* ln_b     = (const float*)d_in[8];
  const float* w_hid    = (const float*)d_in[9];
  const float* b_hid    = (const float*)d_in[10];
  const float* w_skill  = (const float*)d_in[11];
  const float* b_skill  = (const float*)d_in[12];
  const float* w_prob   = (const float*)d_in[13];
  const float* b_prob   = (const float*)d_in[14];
  const float* q_matrix = (const float*)d_in[15];
  float* out = (float*)d_out;

  char* ws = (char*)d_ws;
  const size_t SZ = (size_t)BT * Hh * sizeof(float);   // 33.5 MB
  float* x    = (float*)(ws);
  float* q    = (float*)(ws + SZ);
  float* kk   = (float*)(ws + 2*SZ);
  float* vv   = (float*)(ws + 3*SZ);
  float* att  = (float*)(ws + 4*SZ);
  float* ypre = q;  // q dead after attention
  unsigned long long* pmask = (unsigned long long*)(ws + 5*SZ);
  unsigned long long* smask = pmask + BT;

  k_skill_mask<<<4, 256, 0, stream>>>(q_matrix, smask);
  k_pid_mask<<<BT/256, 256, 0, stream>>>(prob_x, smask, pmask);
  k_build_x<<<BT, 256, 0, stream>>>(prob_x, emb, x);

  dim3 gg(Hh/128, BT/128);  // (8, 64)
  k_gemm128<<<gg, 256, 0, stream>>>(x, wq, q,  nullptr, 0.125f, 1);
  k_gemm128<<<gg, 256, 0, stream>>>(x, wk, kk, nullptr, 1.f,    1);
  k_gemm128<<<gg, 256, 0, stream>>>(x, wv, vv, nullptr, 1.f,    1);

  k_attn<<<dim3(Tt/4, Bb*NHd), 256, 0, stream>>>(q, kk, vv, pmask, att);

  k_gemm128<<<gg, 256, 0, stream>>>(att, wo, ypre, x, 1.f, 0);

  k_head<<<BT, 256, 0, stream>>>(ypre, prob_y2, ln_g, ln_b,
                                 w_hid, b_hid, w_skill, b_skill,
                                 w_prob, b_prob, out);
}

// Round 2
// 1256.146 us; speedup vs baseline: 1.7072x; 1.7072x over previous
//
#include <hip/hip_runtime.h>
#include <hip/hip_bf16.h>

#define Bb 16
#define Tt 512
#define Hh 1024
#define NHd 16
#define HD 64
#define BT (Bb*Tt)
#define NSK 50
#define NIT 1000

typedef __attribute__((ext_vector_type(8))) short bf16x8;
typedef __attribute__((ext_vector_type(4))) float f32x4;

__device__ inline unsigned short f2bf(float x){
  union { float f; unsigned u; } v; v.f = x;
  unsigned r = v.u + 0x7fffu + ((v.u >> 16) & 1u);
  return (unsigned short)(r >> 16);
}

// ---------------- skill masks: item -> bitmask of skills ----------------
__global__ void k_skill_mask(const float* __restrict__ qm, unsigned long long* __restrict__ smask){
  int p = blockIdx.x*blockDim.x + threadIdx.x;
  if (p >= NIT) return;
  unsigned long long m = 0ull;
  #pragma unroll
  for (int s = 0; s < NSK; s++)
    if (qm[s*NIT + p] != 0.f) m |= (1ull << s);
  smask[p] = m;
}

__global__ void k_pid_mask(const int* __restrict__ prob_x,
                           const unsigned long long* __restrict__ smask,
                           unsigned long long* __restrict__ pmask){
  int i = blockIdx.x*blockDim.x + threadIdx.x;
  if (i >= BT) return;
  int pid = (prob_x[i] - 4) >> 1;
  pmask[i] = smask[pid];
}

// ---------------- x = emb[prob_x] + position encoding ----------------
__global__ void k_build_x(const int* __restrict__ prob_x, const float* __restrict__ emb,
                          float* __restrict__ x){
  int bt = blockIdx.x;
  int tid = threadIdx.x;
  int t = bt & (Tt - 1);
  int ix = prob_x[bt];
  const float LOG_INC = 0.0180241495f;   // ln(10000)/511
  for (int h = tid; h < Hh; h += 256){
    int j = h >> 1;
    float ang = (float)t * expf(-(float)j * LOG_INC);
    float pe = (h & 1) ? cosf(ang) : sinf(ang);
    x[(size_t)bt*Hh + h] = emb[(size_t)ix*Hh + h] + pe;
  }
}

// ---------------- fp32 GEMM, 128x128 tile, 8x8 per thread ----------------
// A: MxK row-major (M=8192, K=1024), Bw: KxN row-major (N=1024).
// mode 0: fp32, C[m*N+c] = acc + res[m*N+c]
// mode 1: bf16, C[(b,n,t,d)] = bf16(acc*scale)
// mode 2: bf16, C[(b,n,d,t)] = bf16(acc)        (transposed V for flash attn)
__global__ __launch_bounds__(256) void k_gemm128(
    const float* __restrict__ A, const float* __restrict__ Bw,
    void* __restrict__ Cout, const float* __restrict__ res,
    float scale, int mode)
{
  const int K = 1024, N = 1024;
  __shared__ float As[16][132];
  __shared__ float Bs[16][132];
  int tid = threadIdx.x;
  int tx = tid & 15, ty = tid >> 4;
  int row0 = blockIdx.y * 128, col0 = blockIdx.x * 128;
  float acc[8][8];
  #pragma unroll
  for (int i = 0; i < 8; i++)
    #pragma unroll
    for (int j = 0; j < 8; j++) acc[i][j] = 0.f;

  int ar = tid >> 2, ac = (tid & 3) * 4;
  int br = tid >> 5, bc = (tid & 31) * 4;
  const float* Ap0 = A + (size_t)(row0 + ar) * K + ac;
  const float* Ap1 = A + (size_t)(row0 + ar + 64) * K + ac;
  const float* Bp0 = Bw + (size_t)br * N + col0 + bc;
  const float* Bp1 = Bw + (size_t)(br + 8) * N + col0 + bc;

  for (int k0 = 0; k0 < K; k0 += 16){
    float4 a0 = *(const float4*)(Ap0 + k0);
    float4 a1 = *(const float4*)(Ap1 + k0);
    float4 b0 = *(const float4*)(Bp0 + (size_t)k0 * N);
    float4 b1 = *(const float4*)(Bp1 + (size_t)k0 * N);
    __syncthreads();
    As[ac+0][ar] = a0.x; As[ac+1][ar] = a0.y; As[ac+2][ar] = a0.z; As[ac+3][ar] = a0.w;
    As[ac+0][ar+64] = a1.x; As[ac+1][ar+64] = a1.y; As[ac+2][ar+64] = a1.z; As[ac+3][ar+64] = a1.w;
    *(float4*)&Bs[br][bc]   = b0;
    *(float4*)&Bs[br+8][bc] = b1;
    __syncthreads();
    #pragma unroll
    for (int kk = 0; kk < 16; kk++){
      float a[8], b[8];
      *(float4*)(a)   = *(const float4*)&As[kk][ty*8];
      *(float4*)(a+4) = *(const float4*)&As[kk][ty*8+4];
      *(float4*)(b)   = *(const float4*)&Bs[kk][tx*8];
      *(float4*)(b+4) = *(const float4*)&Bs[kk][tx*8+4];
      #pragma unroll
      for (int i = 0; i < 8; i++)
        #pragma unroll
        for (int j = 0; j < 8; j++)
          acc[i][j] = fmaf(a[i], b[j], acc[i][j]);
    }
  }

  if (mode == 0){
    float* C = (float*)Cout;
    #pragma unroll
    for (int i = 0; i < 8; i++){
      int m = row0 + ty*8 + i;
      #pragma unroll
      for (int j = 0; j < 8; j++){
        int c = col0 + tx*8 + j;
        size_t idx = (size_t)m*N + c;
        C[idx] = acc[i][j] + res[idx];
      }
    }
  } else if (mode == 1){
    unsigned short* C = (unsigned short*)Cout;
    int c0 = col0 + tx*8;
    int n_ = c0 >> 6, d0 = c0 & 63;
    #pragma unroll
    for (int i = 0; i < 8; i++){
      int m = row0 + ty*8 + i;
      int b_ = m >> 9, t_ = m & (Tt-1);
      alignas(16) unsigned short tmp[8];
      #pragma unroll
      for (int j = 0; j < 8; j++) tmp[j] = f2bf(acc[i][j] * scale);
      *(uint4*)(C + ((((size_t)b_*NHd + n_)*Tt + t_)*HD + d0)) = *(const uint4*)tmp;
    }
  } else {
    unsigned short* C = (unsigned short*)Cout;
    int t0r = row0 + ty*8;
    int b_ = t0r >> 9, tloc = t0r & (Tt-1);
    #pragma unroll
    for (int j = 0; j < 8; j++){
      int c = col0 + tx*8 + j;
      int n_ = c >> 6, d_ = c & 63;
      alignas(16) unsigned short tmp[8];
      #pragma unroll
      for (int i = 0; i < 8; i++) tmp[i] = f2bf(acc[i][j]);
      *(uint4*)(C + ((((size_t)b_*NHd + n_)*HD + d_)*Tt + tloc)) = *(const uint4*)tmp;
    }
  }
}

// ---------------- MFMA flash attention ----------------
// q,k: bf16 (b,n,t,d); vt: bf16 (b,n,d,t); out: fp32 (b,t,n,d).
// Block: 4 waves, one (b,n) and a 64-row f-tile; wave w owns 16 f-rows.
__global__ __launch_bounds__(256) void k_flash(
    const unsigned short* __restrict__ qb, const unsigned short* __restrict__ kb,
    const unsigned short* __restrict__ vtb, const unsigned long long* __restrict__ pmask,
    float* __restrict__ o)
{
  __shared__ unsigned short sK[64*64];      // [t][d] swizzled
  __shared__ unsigned short sV[64*64];      // [d][t] swizzled
  __shared__ unsigned short sP[4][16*64];   // per-wave [f][t] swizzled

  const int tid = threadIdx.x;
  const int w = tid >> 6, lane = tid & 63;
  const int c = lane & 15, g = lane >> 4;
  const int Fblk = blockIdx.x;
  const int bn = blockIdx.y;
  const int b = bn >> 4, n = bn & 15;
  const int F0 = Fblk * 64;
  const int f0w = F0 + w * 16;

  // Q fragments (A-operand): lane holds Q[f0w + c][8g..8g+7 (+32)]
  const unsigned short* qrow = qb + ((size_t)bn*Tt + f0w + c)*HD + 8*g;
  bf16x8 qf0 = *(const bf16x8*)(qrow);
  bf16x8 qf1 = *(const bf16x8*)(qrow + 32);

  const unsigned long long* pmb = pmask + b*Tt;
  unsigned long long mf[4]; int fr[4];
  #pragma unroll
  for (int r = 0; r < 4; r++){ fr[r] = f0w + 4*g + r; mf[r] = pmb[fr[r]]; }

  f32x4 O[4];
  #pragma unroll
  for (int dt = 0; dt < 4; dt++) O[dt] = (f32x4){0.f,0.f,0.f,0.f};
  float m_run[4] = {-1e30f,-1e30f,-1e30f,-1e30f};
  float l_run[4] = {0.f,0.f,0.f,0.f};

  const char* kbase = (const char*)(kb + (size_t)bn*Tt*HD);
  const char* vbase = (const char*)(vtb + (size_t)bn*HD*Tt);
  char* sKc = (char*)sK; char* sVc = (char*)sV;
  char* sPw = (char*)(sP[w]);

  const int nT = Fblk + 1;
  for (int it = 0; it < nT; ++it){
    const int t0 = it * 64;
    __syncthreads();
    // ---- cooperative staging: K tile [64t][64d], V tile [64d][64t], XOR-swizzled
    {
      int s0 = tid, s1 = 256 + tid;
      int r0 = s0 >> 3, c0_ = s0 & 7;
      int r1 = s1 >> 3, c1_ = s1 & 7;
      uint4 kv0 = *(const uint4*)(kbase + (size_t)(t0 + r0)*128 + c0_*16);
      uint4 kv1 = *(const uint4*)(kbase + (size_t)(t0 + r1)*128 + c1_*16);
      uint4 vv0 = *(const uint4*)(vbase + (size_t)r0*1024 + t0*2 + c0_*16);
      uint4 vv1 = *(const uint4*)(vbase + (size_t)r1*1024 + t0*2 + c1_*16);
      *(uint4*)(sKc + r0*128 + ((c0_ ^ (r0 & 7))*16)) = kv0;
      *(uint4*)(sKc + r1*128 + ((c1_ ^ (r1 & 7))*16)) = kv1;
      *(uint4*)(sVc + r0*128 + ((c0_ ^ (r0 & 7))*16)) = vv0;
      *(uint4*)(sVc + r1*128 + ((c1_ ^ (r1 & 7))*16)) = vv1;
    }
    __syncthreads();

    if (t0 > f0w + 15) continue;   // wave fully above diagonal; barriers stay aligned

    // ---- S = Q.K^T : 4 sub-tiles of 16 t-columns
    f32x4 S[4];
    #pragma unroll
    for (int ts = 0; ts < 4; ts++){
      int tl = ts*16 + c;
      const char* kr = sKc + tl*128;
      int sw = (tl & 7) << 4;
      bf16x8 kf0 = *(const bf16x8*)(kr + ((g*16) ^ sw));
      bf16x8 kf1 = *(const bf16x8*)(kr + ((64 + g*16) ^ sw));
      f32x4 a = (f32x4){0.f,0.f,0.f,0.f};
      a = __builtin_amdgcn_mfma_f32_16x16x32_bf16(qf0, kf0, a, 0, 0, 0);
      a = __builtin_amdgcn_mfma_f32_16x16x32_bf16(qf1, kf1, a, 0, 0, 0);
      S[ts] = a;
    }

    unsigned long long pmt[4];
    #pragma unroll
    for (int ts = 0; ts < 4; ts++) pmt[ts] = pmb[t0 + ts*16 + c];

    // ---- mask + online softmax (rows f = f0w + 4g + r; cols t = t0 + ts*16 + c)
    float al[4];
    #pragma unroll
    for (int r = 0; r < 4; r++){
      #pragma unroll
      for (int ts = 0; ts < 4; ts++){
        int t = t0 + ts*16 + c;
        bool ok = (fr[r] == 0) ? (t == 0)
                 : (t > 0 && t <= fr[r] && ((pmt[ts] & mf[r]) != 0ull));
        if (!ok) S[ts][r] = -1e30f;
      }
      float mx = fmaxf(fmaxf(S[0][r], S[1][r]), fmaxf(S[2][r], S[3][r]));
      mx = fmaxf(mx, __shfl_xor(mx, 1));
      mx = fmaxf(mx, __shfl_xor(mx, 2));
      mx = fmaxf(mx, __shfl_xor(mx, 4));
      mx = fmaxf(mx, __shfl_xor(mx, 8));
      float mnew = fmaxf(m_run[r], mx);
      al[r] = __expf(m_run[r] - mnew);
      m_run[r] = mnew;
      l_run[r] *= al[r];
    }
    #pragma unroll
    for (int dt = 0; dt < 4; dt++)
      #pragma unroll
      for (int r = 0; r < 4; r++) O[dt][r] *= al[r];

    // ---- P = exp(S - m), bf16, into per-wave LDS tile (swizzled)
    #pragma unroll
    for (int ts = 0; ts < 4; ts++){
      #pragma unroll
      for (int r = 0; r < 4; r++){
        float pv = __expf(S[ts][r] - m_run[r]);
        l_run[r] += pv;
        int prow = 4*g + r;
        int pbyte = (prow*128 + (ts*16 + c)*2) ^ ((prow & 7) << 4);
        *(unsigned short*)(sPw + pbyte) = f2bf(pv);
      }
    }

    // ---- O += P.V  (A = P from LDS, B = V^T tile)
    {
      const char* pr = sPw + c*128;
      int swp = (c & 7) << 4;
      bf16x8 pa0 = *(const bf16x8*)(pr + ((g*16) ^ swp));
      bf16x8 pa1 = *(const bf16x8*)(pr + ((64 + g*16) ^ swp));
      #pragma unroll
      for (int dt = 0; dt < 4; dt++){
        const char* vr = sVc + (dt*16 + c)*128;
        int swv = (c & 7) << 4;
        bf16x8 vf0 = *(const bf16x8*)(vr + ((g*16) ^ swv));
        bf16x8 vf1 = *(const bf16x8*)(vr + ((64 + g*16) ^ swv));
        O[dt] = __builtin_amdgcn_mfma_f32_16x16x32_bf16(pa0, vf0, O[dt], 0, 0, 0);
        O[dt] = __builtin_amdgcn_mfma_f32_16x16x32_bf16(pa1, vf1, O[dt], 0, 0, 0);
      }
    }
  }

  // ---- epilogue: normalize, write (b, f, n, d) fp32
  float inv[4];
  #pragma unroll
  for (int r = 0; r < 4; r++){
    float l = l_run[r];
    l += __shfl_xor(l, 1);
    l += __shfl_xor(l, 2);
    l += __shfl_xor(l, 4);
    l += __shfl_xor(l, 8);
    inv[r] = 1.f / l;
  }
  float* ob = o + (((size_t)b*Tt + f0w)*NHd + n)*HD;
  #pragma unroll
  for (int dt = 0; dt < 4; dt++)
    #pragma unroll
    for (int r = 0; r < 4; r++){
      int floc = 4*g + r;
      ob[(size_t)floc*(NHd*HD) + dt*16 + c] = O[dt][r] * inv[r];
    }
}

// ---------------- LN + MLP head + gather, one block per (b,t) row ----------------
__global__ __launch_bounds__(256) void k_head(
    const float* __restrict__ ypre, const int* __restrict__ prob_y2,
    const float* __restrict__ gamma, const float* __restrict__ beta,
    const float* __restrict__ w_hid, const float* __restrict__ b_hid,
    const float* __restrict__ w_skill, const float* __restrict__ b_skill,
    const float* __restrict__ w_prob, const float* __restrict__ b_prob,
    float* __restrict__ out)
{
  int bt = blockIdx.x;
  int tid = threadIdx.x;
  __shared__ float yn[Hh];
  __shared__ float red[256];
  __shared__ float hbuf[128];
  __shared__ float sk[64];
  const float* yr = ypre + (size_t)bt*Hh;

  float vals[4], s1 = 0.f, s2 = 0.f;
  #pragma unroll
  for (int i = 0; i < 4; i++){
    float vv = yr[tid + 256*i];
    vals[i] = vv; s1 += vv; s2 += vv*vv;
  }
  red[tid] = s1; __syncthreads();
  for (int s = 128; s; s >>= 1){ if (tid < s) red[tid] += red[tid+s]; __syncthreads(); }
  float mu = red[0] * (1.f/Hh); __syncthreads();
  red[tid] = s2; __syncthreads();
  for (int s = 128; s; s >>= 1){ if (tid < s) red[tid] += red[tid+s]; __syncthreads(); }
  float var = red[0] * (1.f/Hh) - mu*mu;
  float inv = rsqrtf(var + 1e-3f);
  #pragma unroll
  for (int i = 0; i < 4; i++){
    int h = tid + 256*i;
    yn[h] = (vals[i] - mu) * inv * gamma[h] + beta[h];
  }
  __syncthreads();

  int j = tid & 127, part = tid >> 7;
  float hs = 0.f;
  if (j < 100){
    int i0 = part * 512;
    for (int i = i0; i < i0 + 512; i++) hs += yn[i] * w_hid[i*100 + j];
  }
  red[tid] = hs; __syncthreads();
  if (tid < 128){
    float hv = red[tid] + red[tid + 128];
    if (tid < 100) hbuf[tid] = fmaxf(hv + b_hid[tid], 0.f);
  }
  __syncthreads();

  if (tid < 50){
    float s = b_skill[tid];
    for (int i = 0; i < 100; i++) s += hbuf[i] * w_skill[i*50 + tid];
    sk[tid] = s;
  }
  __syncthreads();

  if (tid == 0){
    int np = (prob_y2[bt] - 4) >> 1;
    float z = b_prob[np];
    #pragma unroll
    for (int s = 0; s < NSK; s++) z += sk[s] * w_prob[s*NIT + np];
    out[bt] = 1.f / (1.f + expf(-z));
  }
}

extern "C" void kernel_launch(void* const* d_in, const int* in_sizes, int n_in,
                              void* d_out, int out_size, void* d_ws, size_t ws_size,
                              hipStream_t stream)
{
  const int*   prob_x   = (const int*)d_in[0];
  const int*   prob_y2  = (const int*)d_in[1];
  const float* emb      = (const float*)d_in[2];
  const float* wq       = (const float*)d_in[3];
  const float* wk       = (const float*)d_in[4];
  const float* wv       = (const float*)d_in[5];
  const float* wo       = (const float*)d_in[6];
  const float* ln_g     = (const float*)d_in[7];
  const float* ln_b     = (const float*)d_in[8];
  const float* w_hid    = (const float*)d_in[9];
  const float* b_hid    = (const float*)d_in[10];
  const float* w_skill  = (const float*)d_in[11];
  const float* b_skill  = (const float*)d_in[12];
  const float* w_prob   = (const float*)d_in[13];
  const float* b_prob   = (const float*)d_in[14];
  const float* q_matrix = (const float*)d_in[15];
  float* out = (float*)d_out;

  char* ws = (char*)d_ws;
  const size_t MB32 = (size_t)BT * Hh * sizeof(float);          // 32 MiB
  const size_t MB16 = (size_t)BT * Hh * sizeof(unsigned short); // 16 MiB
  float* x    = (float*)(ws);
  float* att  = (float*)(ws + MB32);
  float* ypre = (float*)(ws + 2*MB32);
  unsigned short* qbuf = (unsigned short*)(ws + 3*MB32);
  unsigned short* kbuf = (unsigned short*)(ws + 3*MB32 + MB16);
  unsigned short* vtbuf= (unsigned short*)(ws + 3*MB32 + 2*MB16);
  unsigned long long* pmask = (unsigned long long*)(ws + 3*MB32 + 3*MB16);
  unsigned long long* smask = pmask + BT;

  k_skill_mask<<<4, 256, 0, stream>>>(q_matrix, smask);
  k_pid_mask<<<BT/256, 256, 0, stream>>>(prob_x, smask, pmask);
  k_build_x<<<BT, 256, 0, stream>>>(prob_x, emb, x);

  dim3 gg(Hh/128, BT/128);  // (8, 64)
  k_gemm128<<<gg, 256, 0, stream>>>(x, wq, qbuf,  nullptr, 0.125f, 1);
  k_gemm128<<<gg, 256, 0, stream>>>(x, wk, kbuf,  nullptr, 1.f,    1);
  k_gemm128<<<gg, 256, 0, stream>>>(x, wv, vtbuf, nullptr, 1.f,    2);

  k_flash<<<dim3(Tt/64, Bb*NHd), 256, 0, stream>>>(qbuf, kbuf, vtbuf, pmask, att);

  k_gemm128<<<gg, 256, 0, stream>>>(att, wo, ypre, x, 1.f, 0);

  k_head<<<BT, 256, 0, stream>>>(ypre, prob_y2, ln_g, ln_b,
                                 w_hid, b_hid, w_skill, b_skill,
                                 w_prob, b_prob, out);
}

// Round 3
// 324.388 us; speedup vs baseline: 6.6109x; 3.8724x over previous
//
#include <hip/hip_runtime.h>
#include <hip/hip_bf16.h>

#define Bb 16
#define Tt 512
#define Hh 1024
#define NHd 16
#define HD 64
#define BT (Bb*Tt)
#define NSK 50
#define NIT 1000

typedef __attribute__((ext_vector_type(8))) short bf16x8;
typedef __attribute__((ext_vector_type(4))) float f32x4;
typedef unsigned short u16;
typedef unsigned int u32;

__device__ inline u16 f2bf(float x){
  union { float f; u32 u; } v; v.f = x;
  u32 r = v.u + 0x7fffu + ((v.u >> 16) & 1u);
  return (u16)(r >> 16);
}
__device__ inline float bf2f(u32 u){
  union { u32 uu; float f; } v; v.uu = u << 16; return v.f;
}
__device__ inline void gload_lds16(const void* g, void* l){
  __builtin_amdgcn_global_load_lds(
    (const __attribute__((address_space(1))) u32*)g,
    (__attribute__((address_space(3))) u32*)l, 16, 0, 0);
}

// ---------------- skill masks ----------------
__global__ void k_skill_mask(const float* __restrict__ qm, unsigned long long* __restrict__ smask){
  int p = blockIdx.x*blockDim.x + threadIdx.x;
  if (p >= NIT) return;
  unsigned long long m = 0ull;
  #pragma unroll
  for (int s = 0; s < NSK; s++)
    if (qm[s*NIT + p] != 0.f) m |= (1ull << s);
  smask[p] = m;
}

__global__ void k_pid_mask(const int* __restrict__ prob_x,
                           const unsigned long long* __restrict__ smask,
                           unsigned long long* __restrict__ pmask){
  int i = blockIdx.x*blockDim.x + threadIdx.x;
  if (i >= BT) return;
  int pid = (prob_x[i] - 4) >> 1;
  pmask[i] = smask[pid];
}

// ---------------- position-encoding table [512][1024] ----------------
__global__ void k_pe(float* __restrict__ pe){
  int t = blockIdx.x, tid = threadIdx.x;
  int h0 = tid*4;
  int j0 = h0 >> 1;
  const float LOG_INC = 0.0180241495f;   // ln(10000)/511
  float a0 = (float)t * expf(-(float)j0 * LOG_INC);
  float a1 = (float)t * expf(-(float)(j0+1) * LOG_INC);
  float4 v = { sinf(a0), cosf(a0), sinf(a1), cosf(a1) };
  *(float4*)(pe + (size_t)t*Hh + h0) = v;
}

// ---------------- x = emb[prob_x] + pe : fp32 + bf16 copies ----------------
__global__ __launch_bounds__(256) void k_build_x2(
    const int* __restrict__ prob_x, const float* __restrict__ emb,
    const float* __restrict__ pe, float* __restrict__ x, u16* __restrict__ xb){
  int bt = blockIdx.x, tid = threadIdx.x;
  int t = bt & (Tt-1);
  int ix = prob_x[bt];
  int h = tid*4;
  float4 e = *(const float4*)(emb + (size_t)ix*Hh + h);
  float4 p = *(const float4*)(pe + (size_t)t*Hh + h);
  float4 v = { e.x+p.x, e.y+p.y, e.z+p.z, e.w+p.w };
  *(float4*)(x + (size_t)bt*Hh + h) = v;
  alignas(8) u16 tmp[4] = { f2bf(v.x), f2bf(v.y), f2bf(v.z), f2bf(v.w) };
  *(uint2*)(xb + (size_t)bt*Hh + h) = *(const uint2*)tmp;
}

// ---------------- weight transpose: src fp32 [1024][C] -> dst bf16 [Cpad][1024] ----------------
__global__ __launch_bounds__(256) void k_wT(const float* __restrict__ src, u16* __restrict__ dst,
                                            int C, float scale){
  __shared__ float tile[32][33];
  int tx = threadIdx.x & 31, ty = threadIdx.x >> 5;
  int c0 = blockIdx.x*32, r0 = blockIdx.y*32;
  #pragma unroll
  for (int i = 0; i < 32; i += 8){
    int r = r0 + ty + i, cc = c0 + tx;
    tile[ty+i][tx] = (cc < C) ? src[(size_t)r*C + cc] : 0.f;
  }
  __syncthreads();
  #pragma unroll
  for (int i = 0; i < 32; i += 8){
    int cc = c0 + ty + i, rr = r0 + tx;
    dst[(size_t)cc*1024 + rr] = f2bf(tile[tx][ty+i] * scale);
  }
}

// ---------------- w_prob transpose: [50][1000] -> fp32 [1000][64] ----------------
__global__ void k_wpT(const float* __restrict__ wp, float* __restrict__ wpt){
  int p = blockIdx.x, tid = threadIdx.x;
  if (tid < NSK) wpt[(size_t)p*64 + tid] = wp[(size_t)tid*NIT + p];
}

// ---------------- bf16 MFMA GEMM, 128x128 tile, BK=64, K=1024 ----------------
// A: bf16 [M][1024]; Bt: bf16 [N][1024] (transposed weights).
// mode 0: bf16 scatter (b,head,t,d)          (Q, K)
// mode 1: bf16 scatter (b,head,d,t)          (V transposed)
// mode 2: fp32 [M][1024] = acc + res         (WO + residual)
// mode 3: bf16 [M][128]  = relu(acc + res[col])  (hidden layer; res=b_hid)
__global__ __launch_bounds__(256) void k_gemm_mfma(
    const u16* __restrict__ A, const u16* __restrict__ Bt,
    void* __restrict__ Cout, const float* __restrict__ res, int mode)
{
  __shared__ u16 sA[128*64];
  __shared__ u16 sB[128*64];
  const int tid = threadIdx.x, w = tid >> 6, lane = tid & 63;
  const int c = lane & 15, g = lane >> 4;
  const int row0 = blockIdx.y*128, col0 = blockIdx.x*128;
  const int wr = w >> 1, wc = w & 1;
  const int srl = lane >> 3, scb = lane & 7;   // staging row-local / col-block

  f32x4 acc[4][4];
  #pragma unroll
  for (int mi = 0; mi < 4; mi++)
    #pragma unroll
    for (int ni = 0; ni < 4; ni++) acc[mi][ni] = (f32x4){0.f,0.f,0.f,0.f};

  for (int k0 = 0; k0 < 1024; k0 += 64){
    __syncthreads();
    #pragma unroll
    for (int i = 0; i < 4; i++){
      int arow = 32*w + 8*i + srl;
      int kblk = scb ^ (arow & 7);           // pre-swizzled source (T2, m173 pattern)
      gload_lds16(A  + (size_t)(row0 + arow)*1024 + k0 + kblk*8,
                  (char*)sA + w*4096 + i*1024);
      gload_lds16(Bt + (size_t)(col0 + arow)*1024 + k0 + kblk*8,
                  (char*)sB + w*4096 + i*1024);
    }
    __syncthreads();   // drains vmcnt -> tiles resident

    #pragma unroll
    for (int kh = 0; kh < 2; kh++){
      bf16x8 af[4], bf[4];
      #pragma unroll
      for (int mi = 0; mi < 4; mi++){
        int r = 64*wr + 16*mi + c;
        af[mi] = *(const bf16x8*)((char*)sA + r*128 + (((4*kh + g) ^ (r & 7))*16));
      }
      #pragma unroll
      for (int ni = 0; ni < 4; ni++){
        int r = 64*wc + 16*ni + c;
        bf[ni] = *(const bf16x8*)((char*)sB + r*128 + (((4*kh + g) ^ (r & 7))*16));
      }
      #pragma unroll
      for (int mi = 0; mi < 4; mi++)
        #pragma unroll
        for (int ni = 0; ni < 4; ni++)
          acc[mi][ni] = __builtin_amdgcn_mfma_f32_16x16x32_bf16(af[mi], bf[ni], acc[mi][ni], 0, 0, 0);
    }
  }

  if (mode == 0){
    u16* C = (u16*)Cout;
    #pragma unroll
    for (int mi = 0; mi < 4; mi++){
      int m0 = row0 + 64*wr + 16*mi + 4*g;
      int bb = m0 >> 9, t0 = m0 & (Tt-1);
      #pragma unroll
      for (int ni = 0; ni < 4; ni++){
        int col = col0 + 64*wc + 16*ni + c;
        int hd_ = col >> 6, d_ = col & 63;
        u16* base = C + (((size_t)bb*NHd + hd_)*Tt + t0)*HD + d_;
        #pragma unroll
        for (int r = 0; r < 4; r++) base[(size_t)r*HD] = f2bf(acc[mi][ni][r]);
      }
    }
  } else if (mode == 1){
    u16* C = (u16*)Cout;
    #pragma unroll
    for (int mi = 0; mi < 4; mi++){
      int m0 = row0 + 64*wr + 16*mi + 4*g;
      int bb = m0 >> 9, t0 = m0 & (Tt-1);
      #pragma unroll
      for (int ni = 0; ni < 4; ni++){
        int col = col0 + 64*wc + 16*ni + c;
        int hd_ = col >> 6, d_ = col & 63;
        alignas(8) u16 tmp[4];
        #pragma unroll
        for (int r = 0; r < 4; r++) tmp[r] = f2bf(acc[mi][ni][r]);
        *(uint2*)(C + (((size_t)bb*NHd + hd_)*HD + d_)*Tt + t0) = *(const uint2*)tmp;
      }
    }
  } else if (mode == 2){
    float* C = (float*)Cout;
    #pragma unroll
    for (int mi = 0; mi < 4; mi++){
      int m0 = row0 + 64*wr + 16*mi + 4*g;
      #pragma unroll
      for (int ni = 0; ni < 4; ni++){
        int col = col0 + 64*wc + 16*ni + c;
        #pragma unroll
        for (int r = 0; r < 4; r++){
          size_t idx = (size_t)(m0 + r)*Hh + col;
          C[idx] = acc[mi][ni][r] + res[idx];
        }
      }
    }
  } else {
    u16* C = (u16*)Cout;
    #pragma unroll
    for (int mi = 0; mi < 4; mi++){
      int m0 = row0 + 64*wr + 16*mi + 4*g;
      #pragma unroll
      for (int ni = 0; ni < 4; ni++){
        int col = col0 + 64*wc + 16*ni + c;
        float bv = (col < 100) ? res[col] : 0.f;
        #pragma unroll
        for (int r = 0; r < 4; r++)
          C[(size_t)(m0 + r)*128 + col] = f2bf(fmaxf(acc[mi][ni][r] + bv, 0.f));
      }
    }
  }
}

// ---------------- MFMA flash attention (bf16 out) ----------------
__global__ __launch_bounds__(256) void k_flash(
    const u16* __restrict__ qb, const u16* __restrict__ kb,
    const u16* __restrict__ vtb, const unsigned long long* __restrict__ pmask,
    u16* __restrict__ o)
{
  __shared__ u16 sK[64*64];
  __shared__ u16 sV[64*64];
  __shared__ u16 sP[4][16*64];

  const int tid = threadIdx.x;
  const int w = tid >> 6, lane = tid & 63;
  const int c = lane & 15, g = lane >> 4;
  const int Fblk = blockIdx.x;
  const int bn = blockIdx.y;
  const int b = bn >> 4, n = bn & 15;
  const int f0w = Fblk*64 + w*16;

  const u16* qrow = qb + ((size_t)bn*Tt + f0w + c)*HD + 8*g;
  bf16x8 qf0 = *(const bf16x8*)(qrow);
  bf16x8 qf1 = *(const bf16x8*)(qrow + 32);

  const unsigned long long* pmb = pmask + b*Tt;
  unsigned long long mf[4]; int fr[4];
  #pragma unroll
  for (int r = 0; r < 4; r++){ fr[r] = f0w + 4*g + r; mf[r] = pmb[fr[r]]; }

  f32x4 O[4];
  #pragma unroll
  for (int dt = 0; dt < 4; dt++) O[dt] = (f32x4){0.f,0.f,0.f,0.f};
  float m_run[4] = {-1e30f,-1e30f,-1e30f,-1e30f};
  float l_run[4] = {0.f,0.f,0.f,0.f};

  const char* kbase = (const char*)(kb + (size_t)bn*Tt*HD);
  const char* vbase = (const char*)(vtb + (size_t)bn*HD*Tt);
  char* sKc = (char*)sK; char* sVc = (char*)sV;
  char* sPw = (char*)(sP[w]);

  const int nT = Fblk + 1;
  for (int it = 0; it < nT; ++it){
    const int t0 = it * 64;
    __syncthreads();
    {
      int s0 = tid, s1 = 256 + tid;
      int r0 = s0 >> 3, c0_ = s0 & 7;
      int r1 = s1 >> 3, c1_ = s1 & 7;
      uint4 kv0 = *(const uint4*)(kbase + (size_t)(t0 + r0)*128 + c0_*16);
      uint4 kv1 = *(const uint4*)(kbase + (size_t)(t0 + r1)*128 + c1_*16);
      uint4 vv0 = *(const uint4*)(vbase + (size_t)r0*1024 + t0*2 + c0_*16);
      uint4 vv1 = *(const uint4*)(vbase + (size_t)r1*1024 + t0*2 + c1_*16);
      *(uint4*)(sKc + r0*128 + ((c0_ ^ (r0 & 7))*16)) = kv0;
      *(uint4*)(sKc + r1*128 + ((c1_ ^ (r1 & 7))*16)) = kv1;
      *(uint4*)(sVc + r0*128 + ((c0_ ^ (r0 & 7))*16)) = vv0;
      *(uint4*)(sVc + r1*128 + ((c1_ ^ (r1 & 7))*16)) = vv1;
    }
    __syncthreads();

    if (t0 > f0w + 15) continue;

    f32x4 S[4];
    #pragma unroll
    for (int ts = 0; ts < 4; ts++){
      int tl = ts*16 + c;
      const char* kr = sKc + tl*128;
      int sw = (tl & 7) << 4;
      bf16x8 kf0 = *(const bf16x8*)(kr + ((g*16) ^ sw));
      bf16x8 kf1 = *(const bf16x8*)(kr + ((64 + g*16) ^ sw));
      f32x4 a = (f32x4){0.f,0.f,0.f,0.f};
      a = __builtin_amdgcn_mfma_f32_16x16x32_bf16(qf0, kf0, a, 0, 0, 0);
      a = __builtin_amdgcn_mfma_f32_16x16x32_bf16(qf1, kf1, a, 0, 0, 0);
      S[ts] = a;
    }

    unsigned long long pmt[4];
    #pragma unroll
    for (int ts = 0; ts < 4; ts++) pmt[ts] = pmb[t0 + ts*16 + c];

    float al[4];
    #pragma unroll
    for (int r = 0; r < 4; r++){
      #pragma unroll
      for (int ts = 0; ts < 4; ts++){
        int t = t0 + ts*16 + c;
        bool ok = (fr[r] == 0) ? (t == 0)
                 : (t > 0 && t <= fr[r] && ((pmt[ts] & mf[r]) != 0ull));
        if (!ok) S[ts][r] = -1e30f;
      }
      float mx = fmaxf(fmaxf(S[0][r], S[1][r]), fmaxf(S[2][r], S[3][r]));
      mx = fmaxf(mx, __shfl_xor(mx, 1));
      mx = fmaxf(mx, __shfl_xor(mx, 2));
      mx = fmaxf(mx, __shfl_xor(mx, 4));
      mx = fmaxf(mx, __shfl_xor(mx, 8));
      float mnew = fmaxf(m_run[r], mx);
      al[r] = __expf(m_run[r] - mnew);
      m_run[r] = mnew;
      l_run[r] *= al[r];
    }
    #pragma unroll
    for (int dt = 0; dt < 4; dt++)
      #pragma unroll
      for (int r = 0; r < 4; r++) O[dt][r] *= al[r];

    #pragma unroll
    for (int ts = 0; ts < 4; ts++){
      #pragma unroll
      for (int r = 0; r < 4; r++){
        float pv = __expf(S[ts][r] - m_run[r]);
        l_run[r] += pv;
        int prow = 4*g + r;
        int pbyte = (prow*128 + (ts*16 + c)*2) ^ ((prow & 7) << 4);
        *(u16*)(sPw + pbyte) = f2bf(pv);
      }
    }

    {
      const char* pr = sPw + c*128;
      int swp = (c & 7) << 4;
      bf16x8 pa0 = *(const bf16x8*)(pr + ((g*16) ^ swp));
      bf16x8 pa1 = *(const bf16x8*)(pr + ((64 + g*16) ^ swp));
      #pragma unroll
      for (int dt = 0; dt < 4; dt++){
        const char* vr = sVc + (dt*16 + c)*128;
        int swv = (c & 7) << 4;
        bf16x8 vf0 = *(const bf16x8*)(vr + ((g*16) ^ swv));
        bf16x8 vf1 = *(const bf16x8*)(vr + ((64 + g*16) ^ swv));
        O[dt] = __builtin_amdgcn_mfma_f32_16x16x32_bf16(pa0, vf0, O[dt], 0, 0, 0);
        O[dt] = __builtin_amdgcn_mfma_f32_16x16x32_bf16(pa1, vf1, O[dt], 0, 0, 0);
      }
    }
  }

  float inv[4];
  #pragma unroll
  for (int r = 0; r < 4; r++){
    float l = l_run[r];
    l += __shfl_xor(l, 1);
    l += __shfl_xor(l, 2);
    l += __shfl_xor(l, 4);
    l += __shfl_xor(l, 8);
    inv[r] = 1.f / l;
  }
  u16* ob = o + ((size_t)(b*Tt + f0w))*Hh + n*HD;
  #pragma unroll
  for (int dt = 0; dt < 4; dt++)
    #pragma unroll
    for (int r = 0; r < 4; r++)
      ob[(size_t)(4*g + r)*Hh + dt*16 + c] = f2bf(O[dt][r] * inv[r]);
}

// ---------------- LayerNorm -> bf16, one block per row ----------------
__global__ __launch_bounds__(256) void k_ln(
    const float* __restrict__ ypre, const float* __restrict__ gamma,
    const float* __restrict__ beta, u16* __restrict__ yn)
{
  int bt = blockIdx.x, tid = threadIdx.x;
  int lane = tid & 63, w = tid >> 6;
  const float* yr = ypre + (size_t)bt*Hh;
  float4 v = *(const float4*)(yr + tid*4);
  float s1 = v.x+v.y+v.z+v.w;
  float s2 = v.x*v.x+v.y*v.y+v.z*v.z+v.w*v.w;
  #pragma unroll
  for (int off = 1; off < 64; off <<= 1){ s1 += __shfl_xor(s1, off); s2 += __shfl_xor(s2, off); }
  __shared__ float rs[8];
  if (lane == 0){ rs[w] = s1; rs[4+w] = s2; }
  __syncthreads();
  s1 = rs[0]+rs[1]+rs[2]+rs[3];
  s2 = rs[4]+rs[5]+rs[6]+rs[7];
  float mu = s1 * (1.f/Hh);
  float inv = rsqrtf(s2*(1.f/Hh) - mu*mu + 1e-3f);
  float4 gm = *(const float4*)(gamma + tid*4);
  float4 be = *(const float4*)(beta + tid*4);
  alignas(8) u16 tmp[4];
  tmp[0] = f2bf((v.x-mu)*inv*gm.x + be.x);
  tmp[1] = f2bf((v.y-mu)*inv*gm.y + be.y);
  tmp[2] = f2bf((v.z-mu)*inv*gm.z + be.z);
  tmp[3] = f2bf((v.w-mu)*inv*gm.w + be.w);
  *(uint2*)(yn + (size_t)bt*Hh + tid*4) = *(const uint2*)tmp;
}

// ---------------- tail: skills + gather + sigmoid, one wave per row ----------------
__global__ __launch_bounds__(256) void k_tail(
    const u16* __restrict__ hidden, const int* __restrict__ prob_y2,
    const float* __restrict__ w_skill, const float* __restrict__ b_skill,
    const float* __restrict__ wpt, const float* __restrict__ b_prob,
    float* __restrict__ out)
{
  __shared__ float shid[4][104];
  int w = threadIdx.x >> 6, lane = threadIdx.x & 63;
  int row = blockIdx.x*4 + w;
  if (lane < 50){
    u32 hp = *(const u32*)(hidden + (size_t)row*128 + 2*lane);
    shid[w][2*lane]   = bf2f(hp & 0xffffu);
    shid[w][2*lane+1] = bf2f(hp >> 16);
  }
  __syncthreads();
  float s = 0.f;
  if (lane < 50){
    s = b_skill[lane];
    #pragma unroll 4
    for (int i = 0; i < 100; i++) s += shid[w][i] * w_skill[i*NSK + lane];
  }
  int np = (prob_y2[row] - 4) >> 1;
  float z = (lane < 50) ? s * wpt[(size_t)np*64 + lane] : 0.f;
  #pragma unroll
  for (int off = 1; off < 64; off <<= 1) z += __shfl_xor(z, off);
  if (lane == 0) out[row] = 1.f/(1.f + expf(-(z + b_prob[np])));
}

extern "C" void kernel_launch(void* const* d_in, const int* in_sizes, int n_in,
                              void* d_out, int out_size, void* d_ws, size_t ws_size,
                              hipStream_t stream)
{
  const int*   prob_x   = (const int*)d_in[0];
  const int*   prob_y2  = (const int*)d_in[1];
  const float* emb      = (const float*)d_in[2];
  const float* wq       = (const float*)d_in[3];
  const float* wk       = (const float*)d_in[4];
  const float* wv       = (const float*)d_in[5];
  const float* wo       = (const float*)d_in[6];
  const float* ln_g     = (const float*)d_in[7];
  const float* ln_b     = (const float*)d_in[8];
  const float* w_hid    = (const float*)d_in[9];
  const float* b_hid    = (const float*)d_in[10];
  const float* w_skill  = (const float*)d_in[11];
  const float* b_skill  = (const float*)d_in[12];
  const float* w_prob   = (const float*)d_in[13];
  const float* b_prob   = (const float*)d_in[14];
  const float* q_matrix = (const float*)d_in[15];
  float* out = (float*)d_out;

  char* ws = (char*)d_ws;
  const size_t M32 = (size_t)BT*Hh*4;   // 32 MiB
  const size_t M16 = (size_t)BT*Hh*2;   // 16 MiB
  float* x      = (float*)(ws);                   // [0, 32M)
  u16*   xb     = (u16*)(ws + M32);               // [32, 48)
  u16*   qb     = (u16*)(ws + M32 + M16);         // [48, 64)
  u16*   kb     = (u16*)(ws + M32 + 2*M16);       // [64, 80)
  u16*   vtb    = (u16*)(ws + M32 + 3*M16);       // [80, 96)
  u16*   att    = (u16*)(ws + M32 + 4*M16);       // [96, 112)
  float* ypre   = (float*)(ws + M32 + M16);       // alias qb+kb (dead after flash)
  u16*   yn     = (u16*)(ws + M32 + 3*M16);       // alias vtb  (dead after flash)
  u16*   hidden = (u16*)(ws + M32 + 4*M16);       // alias att  (dead after WO gemm)
  char*  aux    = ws + M32 + 5*M16;               // [112, ...)
  float* pe     = (float*)(aux);                          // 2 MiB
  u16*   wqT    = (u16*)(aux + (size_t)2*1024*1024);      // 2 MiB each
  u16*   wkT    = wqT + (size_t)1024*1024;
  u16*   wvT    = wkT + (size_t)1024*1024;
  u16*   woT    = wvT + (size_t)1024*1024;
  u16*   whT    = woT + (size_t)1024*1024;                // 256 KiB
  float* wpt    = (float*)(whT + (size_t)128*1024);       // 256 KiB
  unsigned long long* pmask = (unsigned long long*)(wpt + (size_t)NIT*64);
  unsigned long long* smask = pmask + BT;

  k_skill_mask<<<4, 256, 0, stream>>>(q_matrix, smask);
  k_pid_mask<<<BT/256, 256, 0, stream>>>(prob_x, smask, pmask);
  k_pe<<<Tt, 256, 0, stream>>>(pe);
  k_wT<<<dim3(32,32), 256, 0, stream>>>(wq, wqT, 1024, 0.125f);   // fold HEAD_D^-0.5
  k_wT<<<dim3(32,32), 256, 0, stream>>>(wk, wkT, 1024, 1.f);
  k_wT<<<dim3(32,32), 256, 0, stream>>>(wv, wvT, 1024, 1.f);
  k_wT<<<dim3(32,32), 256, 0, stream>>>(wo, woT, 1024, 1.f);
  k_wT<<<dim3(4,32),  256, 0, stream>>>(w_hid, whT, 100, 1.f);
  k_wpT<<<NIT, 64, 0, stream>>>(w_prob, wpt);
  k_build_x2<<<BT, 256, 0, stream>>>(prob_x, emb, pe, x, xb);

  dim3 gg(8, 64);
  k_gemm_mfma<<<gg, 256, 0, stream>>>(xb, wqT, qb,  nullptr, 0);
  k_gemm_mfma<<<gg, 256, 0, stream>>>(xb, wkT, kb,  nullptr, 0);
  k_gemm_mfma<<<gg, 256, 0, stream>>>(xb, wvT, vtb, nullptr, 1);

  k_flash<<<dim3(Tt/64, Bb*NHd), 256, 0, stream>>>(qb, kb, vtb, pmask, att);

  k_gemm_mfma<<<gg, 256, 0, stream>>>(att, woT, ypre, x, 2);

  k_ln<<<BT, 256, 0, stream>>>(ypre, ln_g, ln_b, yn);

  k_gemm_mfma<<<dim3(1,64), 256, 0, stream>>>(yn, whT, hidden, b_hid, 3);

  k_tail<<<BT/4, 256, 0, stream>>>(hidden, prob_y2, w_skill, b_skill, wpt, b_prob, out);
}

// Round 4
// 229.968 us; speedup vs baseline: 9.3252x; 1.4106x over previous
//
#include <hip/hip_runtime.h>
#include <hip/hip_bf16.h>

#define Bb 16
#define Tt 512
#define Hh 1024
#define NHd 16
#define HD 64
#define BT (Bb*Tt)
#define NSK 50
#define NIT 1000

typedef __attribute__((ext_vector_type(8))) short bf16x8;
typedef __attribute__((ext_vector_type(4))) float f32x4;
typedef unsigned short u16;
typedef unsigned int u32;
typedef unsigned long long u64;

__device__ inline u16 f2bf(float x){
  union { float f; u32 u; } v; v.f = x;
  u32 r = v.u + 0x7fffu + ((v.u >> 16) & 1u);
  return (u16)(r >> 16);
}
__device__ inline float bf2f(u32 u){
  union { u32 uu; float f; } v; v.uu = u << 16; return v.f;
}
__device__ inline void gload_lds16(const void* g, void* l){
  __builtin_amdgcn_global_load_lds(
    (const __attribute__((address_space(1))) u32*)g,
    (__attribute__((address_space(3))) u32*)l, 16, 0, 0);
}

// ---------------- pmask directly from q_matrix ----------------
__global__ void k_pmask(const int* __restrict__ prob_x, const float* __restrict__ qm,
                        u64* __restrict__ pmask){
  int i = blockIdx.x*blockDim.x + threadIdx.x;
  if (i >= BT) return;
  int pid = (prob_x[i] - 4) >> 1;
  u64 m = 0ull;
  #pragma unroll
  for (int s = 0; s < NSK; s++)
    if (qm[s*NIT + pid] != 0.f) m |= (1ull << s);
  pmask[i] = m;
}

// ---------------- position-encoding table [512][1024] ----------------
__global__ void k_pe(float* __restrict__ pe){
  int t = blockIdx.x, tid = threadIdx.x;
  int h0 = tid*4;
  int j0 = h0 >> 1;
  const float LOG_INC = 0.0180241495f;   // ln(10000)/511
  float a0 = (float)t * expf(-(float)j0 * LOG_INC);
  float a1 = (float)t * expf(-(float)(j0+1) * LOG_INC);
  float4 v = { sinf(a0), cosf(a0), sinf(a1), cosf(a1) };
  *(float4*)(pe + (size_t)t*Hh + h0) = v;
}

// ---------------- x = emb[prob_x] + pe : fp32 + bf16 copies ----------------
__global__ __launch_bounds__(256) void k_build_x2(
    const int* __restrict__ prob_x, const float* __restrict__ emb,
    const float* __restrict__ pe, float* __restrict__ x, u16* __restrict__ xb){
  int bt = blockIdx.x, tid = threadIdx.x;
  int t = bt & (Tt-1);
  int ix = prob_x[bt];
  int h = tid*4;
  float4 e = *(const float4*)(emb + (size_t)ix*Hh + h);
  float4 p = *(const float4*)(pe + (size_t)t*Hh + h);
  float4 v = { e.x+p.x, e.y+p.y, e.z+p.z, e.w+p.w };
  *(float4*)(x + (size_t)bt*Hh + h) = v;
  alignas(8) u16 tmp[4] = { f2bf(v.x), f2bf(v.y), f2bf(v.z), f2bf(v.w) };
  *(uint2*)(xb + (size_t)bt*Hh + h) = *(const uint2*)tmp;
}

// ---------------- all weight transposes in one launch ----------------
// z=0..2: wq/wk/wv [1024][1024] -> wqkvT + z*1M (scale 0.125 for z=0)
// z=3:    wo -> woT ; z=4: w_hid [1024][100] -> whT [128][1024] zero-padded
__global__ __launch_bounds__(256) void k_wT_all(
    const float* __restrict__ wq, const float* __restrict__ wk,
    const float* __restrict__ wv, const float* __restrict__ wo,
    const float* __restrict__ wh,
    u16* __restrict__ wqkvT, u16* __restrict__ woT, u16* __restrict__ whT){
  int z = blockIdx.z;
  const float* src; u16* dst; int C = 1024; float scale = 1.f;
  if      (z == 0){ src = wq; dst = wqkvT;                       scale = 0.125f; }
  else if (z == 1){ src = wk; dst = wqkvT + (size_t)1024*1024; }
  else if (z == 2){ src = wv; dst = wqkvT + (size_t)2*1024*1024; }
  else if (z == 3){ src = wo; dst = woT; }
  else            { src = wh; dst = whT; C = 100; if (blockIdx.x >= 4) return; }

  __shared__ float tile[32][33];
  int tx = threadIdx.x & 31, ty = threadIdx.x >> 5;
  int c0 = blockIdx.x*32, r0 = blockIdx.y*32;
  #pragma unroll
  for (int i = 0; i < 32; i += 8){
    int r = r0 + ty + i, cc = c0 + tx;
    tile[ty+i][tx] = (cc < C) ? src[(size_t)r*C + cc] : 0.f;
  }
  __syncthreads();
  #pragma unroll
  for (int i = 0; i < 32; i += 8){
    int cc = c0 + ty + i, rr = r0 + tx;
    dst[(size_t)cc*1024 + rr] = f2bf(tile[tx][ty+i] * scale);
  }
}

// ---------------- w_prob transpose: [50][1000] -> fp32 [1000][64] ----------------
__global__ void k_wpT(const float* __restrict__ wp, float* __restrict__ wpt){
  int p = blockIdx.x, tid = threadIdx.x;
  if (tid < NSK) wpt[(size_t)p*64 + tid] = wp[(size_t)tid*NIT + p];
}

// =========== fused QKV GEMM: A[8192][1024] x BqkvT[3072][1024] ===========
// seg 0 -> Q scatter (b,n,t,d); seg 1 -> K scatter; seg 2 -> V transposed (b,n,d,t)
__global__ __launch_bounds__(256) void k_gemm_qkv(
    const u16* __restrict__ A, const u16* __restrict__ Bt,
    u16* __restrict__ qb, u16* __restrict__ kb, u16* __restrict__ vtb)
{
  __shared__ u16 sA[128*64];
  __shared__ u16 sB[128*64];
  const int tid = threadIdx.x, w = tid >> 6, lane = tid & 63;
  const int c = lane & 15, g = lane >> 4;
  // XCD-chunked swizzle (nwg = 1536)
  int lin = blockIdx.y*24 + blockIdx.x;
  int id2 = (lin & 7)*192 + (lin >> 3);
  int bx = id2 % 24, by = id2 / 24;
  const int row0 = by*128, col0 = bx*128;
  const int wr = w >> 1, wc = w & 1;
  const int srl = lane >> 3, scb = lane & 7;

  f32x4 acc[4][4];
  #pragma unroll
  for (int mi = 0; mi < 4; mi++)
    #pragma unroll
    for (int ni = 0; ni < 4; ni++) acc[mi][ni] = (f32x4){0.f,0.f,0.f,0.f};

  for (int k0 = 0; k0 < 1024; k0 += 64){
    __syncthreads();
    #pragma unroll
    for (int i = 0; i < 4; i++){
      int arow = 32*w + 8*i + srl;
      int kblk = scb ^ (arow & 7);
      gload_lds16(A  + (size_t)(row0 + arow)*1024 + k0 + kblk*8,
                  (char*)sA + w*4096 + i*1024);
      gload_lds16(Bt + (size_t)(col0 + arow)*1024 + k0 + kblk*8,
                  (char*)sB + w*4096 + i*1024);
    }
    __syncthreads();

    #pragma unroll
    for (int kh = 0; kh < 2; kh++){
      bf16x8 af[4], bf[4];
      #pragma unroll
      for (int mi = 0; mi < 4; mi++){
        int r = 64*wr + 16*mi + c;
        af[mi] = *(const bf16x8*)((char*)sA + r*128 + (((4*kh + g) ^ (r & 7))*16));
      }
      #pragma unroll
      for (int ni = 0; ni < 4; ni++){
        int r = 64*wc + 16*ni + c;
        bf[ni] = *(const bf16x8*)((char*)sB + r*128 + (((4*kh + g) ^ (r & 7))*16));
      }
      #pragma unroll
      for (int mi = 0; mi < 4; mi++)
        #pragma unroll
        for (int ni = 0; ni < 4; ni++)
          acc[mi][ni] = __builtin_amdgcn_mfma_f32_16x16x32_bf16(af[mi], bf[ni], acc[mi][ni], 0, 0, 0);
    }
  }

  int seg = col0 >> 10;
  int colL0 = col0 & 1023;
  if (seg < 2){
    u16* C = seg ? kb : qb;
    #pragma unroll
    for (int mi = 0; mi < 4; mi++){
      int m0 = row0 + 64*wr + 16*mi + 4*g;
      int bb = m0 >> 9, t0 = m0 & (Tt-1);
      #pragma unroll
      for (int ni = 0; ni < 4; ni++){
        int col = colL0 + 64*wc + 16*ni + c;
        int hd_ = col >> 6, d_ = col & 63;
        u16* base = C + (((size_t)bb*NHd + hd_)*Tt + t0)*HD + d_;
        #pragma unroll
        for (int r = 0; r < 4; r++) base[(size_t)r*HD] = f2bf(acc[mi][ni][r]);
      }
    }
  } else {
    #pragma unroll
    for (int mi = 0; mi < 4; mi++){
      int m0 = row0 + 64*wr + 16*mi + 4*g;
      int bb = m0 >> 9, t0 = m0 & (Tt-1);
      #pragma unroll
      for (int ni = 0; ni < 4; ni++){
        int col = colL0 + 64*wc + 16*ni + c;
        int hd_ = col >> 6, d_ = col & 63;
        alignas(8) u16 tmp[4];
        #pragma unroll
        for (int r = 0; r < 4; r++) tmp[r] = f2bf(acc[mi][ni][r]);
        *(uint2*)(vtb + (((size_t)bb*NHd + hd_)*HD + d_)*Tt + t0) = *(const uint2*)tmp;
      }
    }
  }
}

// =========== generic MFMA GEMM (modes 2,3) ===========
// mode 2: bf16 [M][1024] = acc + res[idx]  (res fp32)   (WO + residual)
// mode 3: bf16 [M][128]  = relu(acc + res[col])         (hidden; res=b_hid)
__global__ __launch_bounds__(256) void k_gemm_mfma(
    const u16* __restrict__ A, const u16* __restrict__ Bt,
    u16* __restrict__ C, const float* __restrict__ res, int mode)
{
  __shared__ u16 sA[128*64];
  __shared__ u16 sB[128*64];
  const int tid = threadIdx.x, w = tid >> 6, lane = tid & 63;
  const int c = lane & 15, g = lane >> 4;
  int nwg = gridDim.x * gridDim.y;
  int lin = blockIdx.y*gridDim.x + blockIdx.x;
  int q8 = nwg >> 3;
  int id2 = (lin & 7)*q8 + (lin >> 3);
  int bx = id2 % gridDim.x, by = id2 / gridDim.x;
  const int row0 = by*128, col0 = bx*128;
  const int wr = w >> 1, wc = w & 1;
  const int srl = lane >> 3, scb = lane & 7;

  f32x4 acc[4][4];
  #pragma unroll
  for (int mi = 0; mi < 4; mi++)
    #pragma unroll
    for (int ni = 0; ni < 4; ni++) acc[mi][ni] = (f32x4){0.f,0.f,0.f,0.f};

  for (int k0 = 0; k0 < 1024; k0 += 64){
    __syncthreads();
    #pragma unroll
    for (int i = 0; i < 4; i++){
      int arow = 32*w + 8*i + srl;
      int kblk = scb ^ (arow & 7);
      gload_lds16(A  + (size_t)(row0 + arow)*1024 + k0 + kblk*8,
                  (char*)sA + w*4096 + i*1024);
      gload_lds16(Bt + (size_t)(col0 + arow)*1024 + k0 + kblk*8,
                  (char*)sB + w*4096 + i*1024);
    }
    __syncthreads();

    #pragma unroll
    for (int kh = 0; kh < 2; kh++){
      bf16x8 af[4], bf[4];
      #pragma unroll
      for (int mi = 0; mi < 4; mi++){
        int r = 64*wr + 16*mi + c;
        af[mi] = *(const bf16x8*)((char*)sA + r*128 + (((4*kh + g) ^ (r & 7))*16));
      }
      #pragma unroll
      for (int ni = 0; ni < 4; ni++){
        int r = 64*wc + 16*ni + c;
        bf[ni] = *(const bf16x8*)((char*)sB + r*128 + (((4*kh + g) ^ (r & 7))*16));
      }
      #pragma unroll
      for (int mi = 0; mi < 4; mi++)
        #pragma unroll
        for (int ni = 0; ni < 4; ni++)
          acc[mi][ni] = __builtin_amdgcn_mfma_f32_16x16x32_bf16(af[mi], bf[ni], acc[mi][ni], 0, 0, 0);
    }
  }

  if (mode == 2){
    #pragma unroll
    for (int mi = 0; mi < 4; mi++){
      int m0 = row0 + 64*wr + 16*mi + 4*g;
      #pragma unroll
      for (int ni = 0; ni < 4; ni++){
        int col = col0 + 64*wc + 16*ni + c;
        #pragma unroll
        for (int r = 0; r < 4; r++){
          size_t idx = (size_t)(m0 + r)*Hh + col;
          C[idx] = f2bf(acc[mi][ni][r] + res[idx]);
        }
      }
    }
  } else {
    #pragma unroll
    for (int mi = 0; mi < 4; mi++){
      int m0 = row0 + 64*wr + 16*mi + 4*g;
      #pragma unroll
      for (int ni = 0; ni < 4; ni++){
        int col = col0 + 64*wc + 16*ni + c;
        float bv = (col < 100) ? res[col] : 0.f;
        #pragma unroll
        for (int r = 0; r < 4; r++)
          C[(size_t)(m0 + r)*128 + col] = f2bf(fmaxf(acc[mi][ni][r] + bv, 0.f));
      }
    }
  }
}

// =========== MFMA flash attention: 128-row blocks, 4 waves x 32 rows, dbuf ===========
__global__ __launch_bounds__(256, 3) void k_flash(
    const u16* __restrict__ qb, const u16* __restrict__ kb,
    const u16* __restrict__ vtb, const u64* __restrict__ pmask,
    u16* __restrict__ o)
{
  __shared__ u16 sK[2][64*64];
  __shared__ u16 sV[2][64*64];
  __shared__ u16 sP[4][32*64];

  const int tid = threadIdx.x;
  const int w = tid >> 6, lane = tid & 63;
  const int c = lane & 15, g = lane >> 4;
  const int bn = blockIdx.x;
  const int Fblk = 3 - blockIdx.y;          // heavy blocks dispatched first
  const int b = bn >> 4, n = bn & 15;
  const int f0w = Fblk*128 + w*32;

  // Q fragments: fb row-block, rows f0w + 16*fb + c
  bf16x8 qf[2][2];
  #pragma unroll
  for (int fb = 0; fb < 2; fb++){
    const u16* qrow = qb + ((size_t)bn*Tt + f0w + 16*fb + c)*HD + 8*g;
    qf[fb][0] = *(const bf16x8*)(qrow);
    qf[fb][1] = *(const bf16x8*)(qrow + 32);
  }

  const u64* pmb = pmask + b*Tt;
  u64 mf[2][4];
  #pragma unroll
  for (int fb = 0; fb < 2; fb++)
    #pragma unroll
    for (int r = 0; r < 4; r++) mf[fb][r] = pmb[f0w + 16*fb + 4*g + r];

  f32x4 O[2][4];
  #pragma unroll
  for (int fb = 0; fb < 2; fb++)
    #pragma unroll
    for (int dt = 0; dt < 4; dt++) O[fb][dt] = (f32x4){0.f,0.f,0.f,0.f};
  float m_run[2][4], l_run[2][4];
  #pragma unroll
  for (int fb = 0; fb < 2; fb++)
    #pragma unroll
    for (int r = 0; r < 4; r++){ m_run[fb][r] = -1e30f; l_run[fb][r] = 0.f; }

  const char* kbase = (const char*)(kb + (size_t)bn*Tt*HD);
  const char* vbase = (const char*)(vtb + (size_t)bn*HD*Tt);
  char* sPw = (char*)(sP[w]);

  // staging: wave w covers rows 16w..16w+15 of both K and V tiles
  const int srow0 = 16*w + (lane >> 3);
  const int scb = lane & 7;

  #define STAGE(buf, T0)                                                          \
    {                                                                             \
      _Pragma("unroll")                                                           \
      for (int i = 0; i < 2; i++){                                                \
        int row = srow0 + 8*i;                                                    \
        int cb = scb ^ (row & 7);                                                 \
        gload_lds16(kbase + (size_t)((T0) + row)*128 + cb*16,                     \
                    (char*)sK[buf] + w*2048 + i*1024);                            \
        gload_lds16(vbase + (size_t)row*1024 + (T0)*2 + cb*16,                    \
                    (char*)sV[buf] + w*2048 + i*1024);                            \
      }                                                                           \
    }

  const int nT = 2*Fblk + 2;
  STAGE(0, 0)
  __syncthreads();
  int cur = 0;

  for (int it = 0; it < nT; ++it){
    const int t0 = it * 64;
    if (it + 1 < nT) STAGE(cur^1, (it+1)*64)

    if (t0 <= f0w + 31){
      const char* sKc = (const char*)sK[cur];
      const char* sVc = (const char*)sV[cur];

      // ---- S = Q.K^T
      f32x4 S[2][4];
      #pragma unroll
      for (int ts = 0; ts < 4; ts++){
        int tl = ts*16 + c;
        const char* kr = sKc + tl*128;
        int sw = (tl & 7) << 4;
        bf16x8 kf0 = *(const bf16x8*)(kr + ((g*16) ^ sw));
        bf16x8 kf1 = *(const bf16x8*)(kr + ((64 + g*16) ^ sw));
        #pragma unroll
        for (int fb = 0; fb < 2; fb++){
          f32x4 a = (f32x4){0.f,0.f,0.f,0.f};
          a = __builtin_amdgcn_mfma_f32_16x16x32_bf16(qf[fb][0], kf0, a, 0, 0, 0);
          a = __builtin_amdgcn_mfma_f32_16x16x32_bf16(qf[fb][1], kf1, a, 0, 0, 0);
          S[fb][ts] = a;
        }
      }

      u64 pmt[4];
      #pragma unroll
      for (int ts = 0; ts < 4; ts++) pmt[ts] = pmb[t0 + ts*16 + c];

      // ---- mask + online softmax + P store
      #pragma unroll
      for (int fb = 0; fb < 2; fb++){
        float al[4];
        #pragma unroll
        for (int r = 0; r < 4; r++){
          int frr = f0w + 16*fb + 4*g + r;
          u64 mfr = mf[fb][r];
          #pragma unroll
          for (int ts = 0; ts < 4; ts++){
            int t = t0 + ts*16 + c;
            bool ok = (frr == 0) ? (t == 0)
                     : (t > 0 && t <= frr && ((pmt[ts] & mfr) != 0ull));
            if (!ok) S[fb][ts][r] = -1e30f;
          }
          float mx = fmaxf(fmaxf(S[fb][0][r], S[fb][1][r]), fmaxf(S[fb][2][r], S[fb][3][r]));
          mx = fmaxf(mx, __shfl_xor(mx, 1));
          mx = fmaxf(mx, __shfl_xor(mx, 2));
          mx = fmaxf(mx, __shfl_xor(mx, 4));
          mx = fmaxf(mx, __shfl_xor(mx, 8));
          float mnew = fmaxf(m_run[fb][r], mx);
          al[r] = __expf(m_run[fb][r] - mnew);
          m_run[fb][r] = mnew;
          l_run[fb][r] *= al[r];
        }
        #pragma unroll
        for (int dt = 0; dt < 4; dt++)
          #pragma unroll
          for (int r = 0; r < 4; r++) O[fb][dt][r] *= al[r];

        #pragma unroll
        for (int ts = 0; ts < 4; ts++){
          #pragma unroll
          for (int r = 0; r < 4; r++){
            float pv = __expf(S[fb][ts][r] - m_run[fb][r]);
            l_run[fb][r] += pv;
            int prow = 16*fb + 4*g + r;
            int pbyte = (prow*128 + (ts*16 + c)*2) ^ ((prow & 7) << 4);
            *(u16*)(sPw + pbyte) = f2bf(pv);
          }
        }
      }

      // ---- O += P.V
      bf16x8 pa[2][2];
      #pragma unroll
      for (int fb = 0; fb < 2; fb++){
        const char* pr = sPw + (16*fb + c)*128;
        int swp = (c & 7) << 4;
        pa[fb][0] = *(const bf16x8*)(pr + ((g*16) ^ swp));
        pa[fb][1] = *(const bf16x8*)(pr + ((64 + g*16) ^ swp));
      }
      #pragma unroll
      for (int dt = 0; dt < 4; dt++){
        const char* vr = sVc + (dt*16 + c)*128;
        int swv = (c & 7) << 4;
        bf16x8 vf0 = *(const bf16x8*)(vr + ((g*16) ^ swv));
        bf16x8 vf1 = *(const bf16x8*)(vr + ((64 + g*16) ^ swv));
        #pragma unroll
        for (int fb = 0; fb < 2; fb++){
          O[fb][dt] = __builtin_amdgcn_mfma_f32_16x16x32_bf16(pa[fb][0], vf0, O[fb][dt], 0, 0, 0);
          O[fb][dt] = __builtin_amdgcn_mfma_f32_16x16x32_bf16(pa[fb][1], vf1, O[fb][dt], 0, 0, 0);
        }
      }
    }

    __syncthreads();   // drains prefetch vmcnt + guards buffer reuse
    cur ^= 1;
  }
  #undef STAGE

  // ---- epilogue
  #pragma unroll
  for (int fb = 0; fb < 2; fb++){
    float inv[4];
    #pragma unroll
    for (int r = 0; r < 4; r++){
      float l = l_run[fb][r];
      l += __shfl_xor(l, 1);
      l += __shfl_xor(l, 2);
      l += __shfl_xor(l, 4);
      l += __shfl_xor(l, 8);
      inv[r] = 1.f / l;
    }
    u16* ob = o + ((size_t)(b*Tt + f0w + 16*fb))*Hh + n*HD;
    #pragma unroll
    for (int dt = 0; dt < 4; dt++)
      #pragma unroll
      for (int r = 0; r < 4; r++)
        ob[(size_t)(4*g + r)*Hh + dt*16 + c] = f2bf(O[fb][dt][r] * inv[r]);
  }
}

// ---------------- LayerNorm (bf16 in) -> bf16, one block per row ----------------
__global__ __launch_bounds__(256) void k_ln(
    const u16* __restrict__ ypre, const float* __restrict__ gamma,
    const float* __restrict__ beta, u16* __restrict__ yn)
{
  int bt = blockIdx.x, tid = threadIdx.x;
  int lane = tid & 63, w = tid >> 6;
  const u16* yr = ypre + (size_t)bt*Hh;
  uint2 raw = *(const uint2*)(yr + tid*4);
  float v0 = bf2f(raw.x & 0xffffu), v1 = bf2f(raw.x >> 16);
  float v2 = bf2f(raw.y & 0xffffu), v3 = bf2f(raw.y >> 16);
  float s1 = v0+v1+v2+v3;
  float s2 = v0*v0+v1*v1+v2*v2+v3*v3;
  #pragma unroll
  for (int off = 1; off < 64; off <<= 1){ s1 += __shfl_xor(s1, off); s2 += __shfl_xor(s2, off); }
  __shared__ float rs[8];
  if (lane == 0){ rs[w] = s1; rs[4+w] = s2; }
  __syncthreads();
  s1 = rs[0]+rs[1]+rs[2]+rs[3];
  s2 = rs[4]+rs[5]+rs[6]+rs[7];
  float mu = s1 * (1.f/Hh);
  float inv = rsqrtf(s2*(1.f/Hh) - mu*mu + 1e-3f);
  float4 gm = *(const float4*)(gamma + tid*4);
  float4 be = *(const float4*)(beta + tid*4);
  alignas(8) u16 tmp[4];
  tmp[0] = f2bf((v0-mu)*inv*gm.x + be.x);
  tmp[1] = f2bf((v1-mu)*inv*gm.y + be.y);
  tmp[2] = f2bf((v2-mu)*inv*gm.z + be.z);
  tmp[3] = f2bf((v3-mu)*inv*gm.w + be.w);
  *(uint2*)(yn + (size_t)bt*Hh + tid*4) = *(const uint2*)tmp;
}

// ---------------- tail: skills + gather + sigmoid, one wave per row ----------------
__global__ __launch_bounds__(256) void k_tail(
    const u16* __restrict__ hidden, const int* __restrict__ prob_y2,
    const float* __restrict__ w_skill, const float* __restrict__ b_skill,
    const float* __restrict__ wpt, const float* __restrict__ b_prob,
    float* __restrict__ out)
{
  __shared__ float shid[4][104];
  int w = threadIdx.x >> 6, lane = threadIdx.x & 63;
  int row = blockIdx.x*4 + w;
  if (lane < 50){
    u32 hp = *(const u32*)(hidden + (size_t)row*128 + 2*lane);
    shid[w][2*lane]   = bf2f(hp & 0xffffu);
    shid[w][2*lane+1] = bf2f(hp >> 16);
  }
  __syncthreads();
  float s = 0.f;
  if (lane < 50){
    s = b_skill[lane];
    #pragma unroll 4
    for (int i = 0; i < 100; i++) s += shid[w][i] * w_skill[i*NSK + lane];
  }
  int np = (prob_y2[row] - 4) >> 1;
  float z = (lane < 50) ? s * wpt[(size_t)np*64 + lane] : 0.f;
  #pragma unroll
  for (int off = 1; off < 64; off <<= 1) z += __shfl_xor(z, off);
  if (lane == 0) out[row] = 1.f/(1.f + expf(-(z + b_prob[np])));
}

extern "C" void kernel_launch(void* const* d_in, const int* in_sizes, int n_in,
                              void* d_out, int out_size, void* d_ws, size_t ws_size,
                              hipStream_t stream)
{
  const int*   prob_x   = (const int*)d_in[0];
  const int*   prob_y2  = (const int*)d_in[1];
  const float* emb      = (const float*)d_in[2];
  const float* wq       = (const float*)d_in[3];
  const float* wk       = (const float*)d_in[4];
  const float* wv       = (const float*)d_in[5];
  const float* wo       = (const float*)d_in[6];
  const float* ln_g     = (const float*)d_in[7];
  const float* ln_b     = (const float*)d_in[8];
  const float* w_hid    = (const float*)d_in[9];
  const float* b_hid    = (const float*)d_in[10];
  const float* w_skill  = (const float*)d_in[11];
  const float* b_skill  = (const float*)d_in[12];
  const float* w_prob   = (const float*)d_in[13];
  const float* b_prob   = (const float*)d_in[14];
  const float* q_matrix = (const float*)d_in[15];
  float* out = (float*)d_out;

  char* ws = (char*)d_ws;
  const size_t M32 = (size_t)BT*Hh*4;   // 32 MiB
  const size_t M16 = (size_t)BT*Hh*2;   // 16 MiB
  float* x      = (float*)(ws);                   // [0, 32M)
  u16*   xb     = (u16*)(ws + M32);               // [32, 48)
  u16*   qb     = (u16*)(ws + M32 + M16);         // [48, 64)
  u16*   kb     = (u16*)(ws + M32 + 2*M16);       // [64, 80)
  u16*   vtb    = (u16*)(ws + M32 + 3*M16);       // [80, 96)
  u16*   att    = (u16*)(ws + M32 + 4*M16);       // [96, 112)
  u16*   ypre   = qb;      // dead after flash
  u16*   yn     = kb;      // dead after flash
  u16*   hidden = vtb;     // dead after flash
  char*  aux    = ws + M32 + 5*M16;               // [112, ...)
  float* pe     = (float*)(aux);                          // 2 MiB
  u16*   wqkvT  = (u16*)(aux + (size_t)2*1024*1024);      // 6 MiB
  u16*   woT    = wqkvT + (size_t)3*1024*1024;            // 2 MiB
  u16*   whT    = woT + (size_t)1024*1024;                // 256 KiB
  float* wpt    = (float*)(whT + (size_t)128*1024);       // 256 KiB
  u64*   pmask  = (u64*)(wpt + (size_t)NIT*64);

  k_pmask<<<BT/256, 256, 0, stream>>>(prob_x, q_matrix, pmask);
  k_pe<<<Tt, 256, 0, stream>>>(pe);
  k_wT_all<<<dim3(32,32,5), 256, 0, stream>>>(wq, wk, wv, wo, w_hid, wqkvT, woT, whT);
  k_wpT<<<NIT, 64, 0, stream>>>(w_prob, wpt);
  k_build_x2<<<BT, 256, 0, stream>>>(prob_x, emb, pe, x, xb);

  k_gemm_qkv<<<dim3(24,64), 256, 0, stream>>>(xb, wqkvT, qb, kb, vtb);

  k_flash<<<dim3(Bb*NHd, 4), 256, 0, stream>>>(qb, kb, vtb, pmask, att);

  k_gemm_mfma<<<dim3(8,64), 256, 0, stream>>>(att, woT, ypre, x, 2);

  k_ln<<<BT, 256, 0, stream>>>(ypre, ln_g, ln_b, yn);

  k_gemm_mfma<<<dim3(1,64), 256, 0, stream>>>(yn, whT, hidden, b_hid, 3);

  k_tail<<<BT/4, 256, 0, stream>>>(hidden, prob_y2, w_skill, b_skill, wpt, b_prob, out);
}